// Round 2
// baseline (1427.810 us; speedup 1.0000x reference)
//
#include <hip/hip_runtime.h>
#include <hip/hip_fp16.h>

// DeltaNet chunkwise. b=4,h=4,L=4096,dk=dv=256,c=32 -> 16 heads x 128 chunks.
// Phase 1: per-chunk (2048 WGs): normalize, A=stril(kb k^T), register forward-sub
//          solve for u=(I+A)^-1 (v*beta), w=(I+A)^-1 (k*beta), att=tril(q k^T), kT.
// Phase 2: 256 INDEPENDENT waves (16 heads x 16 dv-slices), barrier-free scan.
//          Each wave owns S[256 dk][16 dv] in 64 f32 accumulator VGPRs; the
//          C-layout -> B-fragment transposes of S and u_adj go through
//          wave-private XOR-swizzled LDS (no __syncthreads anywhere).

typedef _Float16 half8 __attribute__((ext_vector_type(8)));
typedef float f32x4 __attribute__((ext_vector_type(4)));
typedef unsigned int u32x2 __attribute__((ext_vector_type(2)));
typedef unsigned int u32x4 __attribute__((ext_vector_type(4)));

__device__ __forceinline__ unsigned short f2h(float f) {
    return __half_as_ushort(__float2half(f));
}
__device__ __forceinline__ float h2f(unsigned short u) {
    return __half2float(__ushort_as_half(u));
}
__device__ __forceinline__ unsigned int pk2(float a, float b) {
    return (unsigned int)f2h(a) | ((unsigned int)f2h(b) << 16);
}

#define MFMA16(a, b, c) __builtin_amdgcn_mfma_f32_16x16x32_f16((a), (b), (c), 0, 0, 0)

// ---------------------------------------------------------------- phase 1
__global__ __launch_bounds__(256, 2) void p1_kernel(
    const float* __restrict__ qg, const float* __restrict__ kg,
    const float* __restrict__ vg, const float* __restrict__ bg,
    unsigned short* __restrict__ qn_w, unsigned short* __restrict__ w_w,
    unsigned short* __restrict__ kT_w, unsigned short* __restrict__ u_w,
    unsigned short* __restrict__ att_w)
{
    __shared__ unsigned short kn_l[32][264];   // normalized k, row-major (pad 264)
    __shared__ unsigned short kb_l[32][264];   // k*beta
    __shared__ unsigned short qn_l[32][264];   // normalized q
    __shared__ float          A_l[32][34];     // strict-lower A, zero elsewhere
    __shared__ unsigned short att_l[32][40];   // tril(q k^T) fp16
    __shared__ unsigned short wst[256][40];    // w column staging [dk][c]
    __shared__ float          beta_l[32];

    const int tid = threadIdx.x;
    const int g   = blockIdx.x;      // global chunk id
    const int bh  = g >> 7;          // head
    const int ci  = g & 127;         // chunk within head
    const size_t inBase = ((size_t)bh * 4096 + (size_t)ci * 32) * 256;

    if (tid < 32) beta_l[tid] = bg[(size_t)bh * 4096 + ci * 32 + tid];

    const int r = tid >> 3, p = tid & 7, d0 = p * 32;   // 8 threads per row
    const float bval = bg[(size_t)bh * 4096 + ci * 32 + r];

    // ---- K: normalize -> kn_l, kb_l ----
    {
        float vals[32]; float ss = 0.f;
        const float4* src = (const float4*)(kg + inBase + (size_t)r * 256 + d0);
        #pragma unroll
        for (int i = 0; i < 8; i++) {
            float4 v4 = src[i];
            vals[4*i+0] = v4.x; vals[4*i+1] = v4.y; vals[4*i+2] = v4.z; vals[4*i+3] = v4.w;
            ss += v4.x*v4.x + v4.y*v4.y + v4.z*v4.z + v4.w*v4.w;
        }
        ss += __shfl_xor(ss, 1); ss += __shfl_xor(ss, 2); ss += __shfl_xor(ss, 4);
        const float rn = rsqrtf(ss);
        unsigned int* dstn = (unsigned int*)&kn_l[r][d0];
        unsigned int* dstb = (unsigned int*)&kb_l[r][d0];
        #pragma unroll
        for (int i = 0; i < 16; i++) {
            float a = vals[2*i] * rn, b = vals[2*i+1] * rn;
            dstn[i] = pk2(a, b);
            dstb[i] = pk2(a * bval, b * bval);
        }
    }
    // ---- Q: normalize -> qn_l + global qn ----
    {
        float vals[32]; float ss = 0.f;
        const float4* src = (const float4*)(qg + inBase + (size_t)r * 256 + d0);
        #pragma unroll
        for (int i = 0; i < 8; i++) {
            float4 v4 = src[i];
            vals[4*i+0] = v4.x; vals[4*i+1] = v4.y; vals[4*i+2] = v4.z; vals[4*i+3] = v4.w;
            ss += v4.x*v4.x + v4.y*v4.y + v4.z*v4.z + v4.w*v4.w;
        }
        ss += __shfl_xor(ss, 1); ss += __shfl_xor(ss, 2); ss += __shfl_xor(ss, 4);
        const float rn = rsqrtf(ss);
        unsigned int pq[16];
        #pragma unroll
        for (int i = 0; i < 16; i++) pq[i] = pk2(vals[2*i] * rn, vals[2*i+1] * rn);
        unsigned int* dstq = (unsigned int*)&qn_l[r][d0];
        #pragma unroll
        for (int i = 0; i < 16; i++) dstq[i] = pq[i];
        u32x4* og = (u32x4*)(qn_w + ((size_t)g * 32 + r) * 256 + d0);
        #pragma unroll
        for (int m = 0; m < 4; m++) {
            u32x4 val; val.x = pq[4*m]; val.y = pq[4*m+1]; val.z = pq[4*m+2]; val.w = pq[4*m+3];
            og[m] = val;
        }
    }
    __syncthreads();

    // ---- MFMA: A = stril(kb kn^T), att = tril(qn kn^T). 4 waves x 1 tile each ----
    {
        const int wid = tid >> 6, lane = tid & 63;
        const int mt = wid >> 1, ntt = wid & 1;
        const int l15 = lane & 15, l4 = lane >> 4;
        f32x4 accA = {0.f, 0.f, 0.f, 0.f}, accT = {0.f, 0.f, 0.f, 0.f};
        #pragma unroll
        for (int kk = 0; kk < 8; kk++) {
            half8 bfr = *(const half8*)&kn_l[ntt*16 + l15][kk*32 + l4*8];
            half8 afr = *(const half8*)&kb_l[mt*16 + l15][kk*32 + l4*8];
            half8 qfr = *(const half8*)&qn_l[mt*16 + l15][kk*32 + l4*8];
            accA = MFMA16(afr, bfr, accA);
            accT = MFMA16(qfr, bfr, accT);
        }
        #pragma unroll
        for (int j = 0; j < 4; j++) {
            int row = mt*16 + l4*4 + j, col = ntt*16 + l15;
            A_l[row][col]   = (row > col)  ? accA[j] : 0.f;
            att_l[row][col] = (row >= col) ? f2h(accT[j]) : (unsigned short)0;
        }
    }
    // ---- kT copy-out (reads kn_l, independent of A_l) ----
    {
        const int dk = tid;
        unsigned short arr[32];
        #pragma unroll
        for (int j = 0; j < 32; j++) arr[j] = kn_l[j][dk];
        u32x4* dst = (u32x4*)(kT_w + ((size_t)g * 256 + dk) * 32);
        #pragma unroll
        for (int m = 0; m < 4; m++) {
            u32x4 val;
            val.x = (unsigned)arr[8*m+0] | ((unsigned)arr[8*m+1] << 16);
            val.y = (unsigned)arr[8*m+2] | ((unsigned)arr[8*m+3] << 16);
            val.z = (unsigned)arr[8*m+4] | ((unsigned)arr[8*m+5] << 16);
            val.w = (unsigned)arr[8*m+6] | ((unsigned)arr[8*m+7] << 16);
            dst[m] = val;
        }
    }
    __syncthreads();

    // ---- register forward substitution: (I+A) x = rhs, per-thread column ----
    {
        const int c = tid;   // 0..255: dv column for u, dk column for w
        float xu[32], xw[32];
        #pragma unroll
        for (int j = 0; j < 32; j++) {
            xu[j] = vg[inBase + (size_t)j * 256 + c] * beta_l[j];
            xw[j] = h2f(kb_l[j][c]);
        }
        #pragma unroll
        for (int i = 1; i < 32; i++) {
            float su = xu[i], sw = xw[i];
            const float2* Ar = (const float2*)(&A_l[i][0]);   // A[i][i]==0 pads odd i
            #pragma unroll
            for (int h = 0; h < (i + 1) / 2; h++) {
                float2 a = Ar[h];
                su -= a.x * xu[2*h] + a.y * xu[2*h+1];
                sw -= a.x * xw[2*h] + a.y * xw[2*h+1];
            }
            xu[i] = su; xw[i] = sw;
        }
        // u out, column-major [dv][chunk] fp16
        unsigned int up[16];
        #pragma unroll
        for (int j = 0; j < 16; j++) up[j] = pk2(xu[2*j], xu[2*j+1]);
        u32x4* du = (u32x4*)(u_w + ((size_t)g * 256 + c) * 32);
        #pragma unroll
        for (int m = 0; m < 4; m++) {
            u32x4 val; val.x = up[4*m]; val.y = up[4*m+1]; val.z = up[4*m+2]; val.w = up[4*m+3];
            du[m] = val;
        }
        // w staged column-major in LDS for row-major global write
        unsigned int* wd = (unsigned int*)&wst[c][0];
        #pragma unroll
        for (int j = 0; j < 16; j++) wd[j] = pk2(xw[2*j], xw[2*j+1]);
    }
    __syncthreads();

    // ---- w copy-out row-major ----
    {
        const int rr = tid >> 3, pp = tid & 7, dd0 = pp * 32;
        unsigned short arr[32];
        #pragma unroll
        for (int i = 0; i < 32; i++) arr[i] = wst[dd0 + i][rr];
        u32x4* dst = (u32x4*)(w_w + ((size_t)g * 32 + rr) * 256 + dd0);
        #pragma unroll
        for (int m = 0; m < 4; m++) {
            u32x4 val;
            val.x = (unsigned)arr[8*m+0] | ((unsigned)arr[8*m+1] << 16);
            val.y = (unsigned)arr[8*m+2] | ((unsigned)arr[8*m+3] << 16);
            val.z = (unsigned)arr[8*m+4] | ((unsigned)arr[8*m+5] << 16);
            val.w = (unsigned)arr[8*m+6] | ((unsigned)arr[8*m+7] << 16);
            dst[m] = val;
        }
    }
    // ---- att copy-out ----
    if (tid < 128) {
        const int rr = tid >> 2, j0 = (tid & 3) * 8;
        u32x4 vv = *(const u32x4*)&att_l[rr][j0];
        *(u32x4*)(att_w + (size_t)g * 1024 + rr * 32 + j0) = vv;
    }
}

// ---------------------------------------------------------------- phase 2
// One wave per (head, dv-16 slice). Barrier-free sequential scan over 128 chunks.
// S[dk=256][dv=16] lives in accS[16] (C-layout); transposes to MFMA B-fragments
// go through wave-private XOR-swizzled LDS (element c <-> position c ^ swz,
// bijective since blocks are 4-aligned and the XOR touches bits >= 3).
__global__ __launch_bounds__(64, 1) void p2_kernel(
    const unsigned short* __restrict__ qn_w, const unsigned short* __restrict__ w_w,
    const unsigned short* __restrict__ kT_w, const unsigned short* __restrict__ u_w,
    const unsigned short* __restrict__ att_w, float* __restrict__ outp)
{
    __shared__ unsigned short Sb[16 * 256];   // [dv=16 rows][256 dk], 512B rows, XOR-swizzled
    __shared__ unsigned short Ub[16 * 32];    // [dv=16 rows][32 c],  64B rows, XOR-swizzled

    const int bid  = blockIdx.x;
    const int bh   = bid & 15;          // head: all 16 slices of a head -> same XCD (bid%8 = bh%8)
    const int dv0  = (bid >> 4) * 16;   // dv slice base
    const int lane = threadIdx.x & 63;
    const int l15  = lane & 15, l4 = lane >> 4;
    const int sswz = (l15 & 7) << 3;    // ushort-unit XOR (16B granule)
    const int uswz = (l15 & 3) << 3;

    unsigned short* SbR = Sb + l15 * 256;
    unsigned short* UbR = Ub + l15 * 32;

    f32x4 accS[16];
    #pragma unroll
    for (int dt = 0; dt < 16; dt++) {
        accS[dt] = (f32x4){0.f, 0.f, 0.f, 0.f};
        u32x2 z; z.x = 0u; z.y = 0u;
        *(u32x2*)&SbR[(dt*16 + l4*4) ^ sswz] = z;
    }

    #pragma unroll 1
    for (int t = 0; t < 128; ++t) {
        const size_t g = (size_t)bh * 128 + t;
        const size_t rowQW = (g * 32 + l15) * 256 + l4 * 8;       // w/q A-frag rows
        const size_t rowK  = (g * 256 + l15) * 32 + l4 * 8;       // kT A-frag rows
        const size_t rowU  = (g * 256 + dv0 + l15) * 32 + l4 * 4; // u C-layout

        // S B-fragments from wave-private LDS (ordered vs prev-iter writes per-wave)
        half8 sB[8];
        #pragma unroll
        for (int kk = 0; kk < 8; kk++)
            sB[kk] = *(const half8*)&SbR[(kk*32 + l4*8) ^ sswz];

        // issue w, u, kT loads early (no barrier ever drains them)
        half8 wf0[8], wf1[8];
        #pragma unroll
        for (int kk = 0; kk < 8; kk++) {
            wf0[kk] = *(const half8*)(w_w + rowQW + kk*32);
            wf1[kk] = *(const half8*)(w_w + rowQW + 16*256 + kk*32);
        }
        u32x2 uc0 = *(const u32x2*)(u_w + rowU);
        u32x2 uc1 = *(const u32x2*)(u_w + rowU + 16);
        half8 kf[16];
        #pragma unroll
        for (int dt = 0; dt < 16; dt++)
            kf[dt] = *(const half8*)(kT_w + rowK + (size_t)dt * 16 * 32);

        // w @ S  (M=32 w-rows, N=16 dv, K=256)
        f32x4 aW0 = {0.f,0.f,0.f,0.f}, aW1 = {0.f,0.f,0.f,0.f};
        #pragma unroll
        for (int kk = 0; kk < 8; kk++) {
            aW0 = MFMA16(wf0[kk], sB[kk], aW0);
            aW1 = MFMA16(wf1[kk], sB[kk], aW1);
        }

        // u_adj = u - w@S (C-layout) -> Ub -> B-fragment
        u32x2 p0, p1;
        p0.x = pk2(h2f((unsigned short)(uc0.x & 0xffff)) - aW0[0],
                   h2f((unsigned short)(uc0.x >> 16))    - aW0[1]);
        p0.y = pk2(h2f((unsigned short)(uc0.y & 0xffff)) - aW0[2],
                   h2f((unsigned short)(uc0.y >> 16))    - aW0[3]);
        p1.x = pk2(h2f((unsigned short)(uc1.x & 0xffff)) - aW1[0],
                   h2f((unsigned short)(uc1.x >> 16))    - aW1[1]);
        p1.y = pk2(h2f((unsigned short)(uc1.y & 0xffff)) - aW1[2],
                   h2f((unsigned short)(uc1.y >> 16))    - aW1[3]);
        *(u32x2*)&UbR[(l4*4) ^ uswz]      = p0;
        *(u32x2*)&UbR[(16 + l4*4) ^ uswz] = p1;
        half8 ub = *(const half8*)&UbR[(l4*8) ^ uswz];

        // issue q, att loads; latency hidden under accS MFMAs + Sb writes
        half8 qf0[8], qf1[8];
        #pragma unroll
        for (int kk = 0; kk < 8; kk++) {
            qf0[kk] = *(const half8*)(qn_w + rowQW + kk*32);
            qf1[kk] = *(const half8*)(qn_w + rowQW + 16*256 + kk*32);
        }
        half8 af0 = *(const half8*)(att_w + g*1024 + (size_t)l15 * 32 + l4*8);
        half8 af1 = *(const half8*)(att_w + g*1024 + (size_t)(16 + l15) * 32 + l4*8);

        // S += kT @ u_adj  (16 independent MFMAs) — the scan's critical path
        #pragma unroll
        for (int dt = 0; dt < 16; dt++)
            accS[dt] = MFMA16(kf[dt], ub, accS[dt]);

        // refresh fp16 S transpose buffer for next step
        #pragma unroll
        for (int dt = 0; dt < 16; dt++) {
            u32x2 sp;
            sp.x = pk2(accS[dt][0], accS[dt][1]);
            sp.y = pk2(accS[dt][2], accS[dt][3]);
            *(u32x2*)&SbR[(dt*16 + l4*4) ^ sswz] = sp;
        }

        // o = q@S + att@u_adj  (uses OLD S still in sB regs) — off critical path
        f32x4 aQ0 = {0.f,0.f,0.f,0.f}, aQ1 = {0.f,0.f,0.f,0.f};
        #pragma unroll
        for (int kk = 0; kk < 8; kk++) {
            aQ0 = MFMA16(qf0[kk], sB[kk], aQ0);
            aQ1 = MFMA16(qf1[kk], sB[kk], aQ1);
        }
        aQ0 = MFMA16(af0, ub, aQ0);
        aQ1 = MFMA16(af1, ub, aQ1);
        float* ob = outp + ((size_t)bh * 4096 + (size_t)t * 32) * 256 + dv0 + l15;
        #pragma unroll
        for (int j = 0; j < 4; j++) {
            ob[(size_t)(l4*4 + j) * 256]      = aQ0[j];
            ob[(size_t)(16 + l4*4 + j) * 256] = aQ1[j];
        }
    }

    // final state S (f32, exact from accumulators) -> d_out tail
    float* so = outp + (size_t)16777216 + ((size_t)bh * 256) * 256 + dv0 + l15;
    #pragma unroll
    for (int dt = 0; dt < 16; dt++) {
        #pragma unroll
        for (int j = 0; j < 4; j++)
            so[(size_t)(dt*16 + l4*4 + j) * 256] = accS[dt][j];
    }
}

// ---------------------------------------------------------------- launch
extern "C" void kernel_launch(void* const* d_in, const int* in_sizes, int n_in,
                              void* d_out, int out_size, void* d_ws, size_t ws_size,
                              hipStream_t stream)
{
    (void)in_sizes; (void)n_in; (void)out_size; (void)ws_size;
    const float* q    = (const float*)d_in[0];
    const float* k    = (const float*)d_in[1];
    const float* v    = (const float*)d_in[2];
    const float* beta = (const float*)d_in[3];
    float* out = (float*)d_out;

    unsigned short* ws  = (unsigned short*)d_ws;
    const size_t SZ = (size_t)2048 * 32 * 256;        // 16.78M fp16 elems per tensor
    unsigned short* qn  = ws;
    unsigned short* ww  = ws + SZ;
    unsigned short* kT  = ws + 2 * SZ;
    unsigned short* uu  = ws + 3 * SZ;
    unsigned short* att = ws + 4 * SZ;                // 2048*1024 elems

    p1_kernel<<<2048, 256, 0, stream>>>(q, k, v, beta, qn, ww, kT, uu, att);
    p2_kernel<<<256, 64, 0, stream>>>(qn, ww, kT, uu, att, out);
}